// Round 2
// baseline (39599.606 us; speedup 1.0000x reference)
//
#include <hip/hip_runtime.h>
#include <math.h>

#define B_   64
#define S_   2048
#define I_   256
#define H_   512
#define K_   768
#define G3   1536

#define NTHR 384                 // 6 waves
#define NWG  128                 // 4 row-groups x 32 col-WGs
#define AST  776                 // LDS k-stride (bf16 elems): 768 + 8 pad (16B aligned, breaks bank aliasing)

typedef __attribute__((ext_vector_type(8))) short  s8v;   // 8 bf16 (4 VGPRs) — MFMA A/B frag
typedef __attribute__((ext_vector_type(4))) float  f4v;   // MFMA C/D frag

static __device__ __forceinline__ unsigned short f2bf(float f) {
    unsigned u = __float_as_uint(f);
    return (unsigned short)((u + 0x7FFFu + ((u >> 16) & 1u)) >> 16);
}
static __device__ __forceinline__ float sigm(float v) { return 1.f / (1.f + __expf(-v)); }
static __device__ __forceinline__ float tanh_(float v) {
    float e = __expf(2.f * v);           // inf/0 saturate correctly -> +-1
    return 1.f - 2.f / (e + 1.f);
}

// ---- transpose [W;U] (768 x 1536 f32, row-major) -> Wb[c][k] bf16 (1536 x 768) ----
__global__ __launch_bounds__(256) void prep_w(const float* __restrict__ W,
                                              const float* __restrict__ U,
                                              unsigned short* __restrict__ Wb) {
    __shared__ float T[64][65];
    const int kb = blockIdx.x * 64;      // 12 blocks over k
    const int cb = blockIdx.y * 64;      // 24 blocks over c
    const int tc = threadIdx.x & 63;
    const int tg = threadIdx.x >> 6;     // 0..3
    for (int rr = 0; rr < 16; ++rr) {
        const int kl = tg * 16 + rr;
        const int k  = kb + kl, c = cb + tc;
        const float v = (k < I_) ? W[(size_t)k * G3 + c] : U[(size_t)(k - I_) * G3 + c];
        T[tc][kl] = v;
    }
    __syncthreads();
    for (int rr = 0; rr < 16; ++rr) {
        const int cl = tg * 16 + rr;
        Wb[(size_t)(cb + cl) * K_ + kb + tc] = f2bf(T[cl][tc]);
    }
}

// ---- persistent LSTM: 4 row-groups (16 rows) x 32 col-WGs (16 j's = 48 gate cols) ----
__global__ __launch_bounds__(NTHR, 1) void lstm_persist(
    const float* __restrict__ x,        // (B,S,I) f32
    const float* __restrict__ bias,     // (3H)
    const unsigned short* __restrict__ Wb,  // (1536,768) bf16
    unsigned short* __restrict__ hex,   // 2 x (64,512) bf16 exchange
    unsigned int* __restrict__ ctr,     // 4 counters, 64B spaced
    float* __restrict__ hidden, float* __restrict__ hf, float* __restrict__ cf)
{
    __shared__ __align__(16) unsigned short Alds[16 * AST];   // [m][k]  (k<256: x_t, k>=256: h)
    __shared__ __align__(16) unsigned short Wlds[48 * AST];   // [c_local][k]
    __shared__ float Glds[3][16][17];
    __shared__ float bl[48];

    const int tid  = threadIdx.x;
    const int lane = tid & 63;
    const int wv   = tid >> 6;          // 0..5
    const int nt   = wv >> 1;           // gate region tile 0..2 (i,g,o)
    const int kp   = wv & 1;            // k-tile parity
    const int mrow = lane & 15;         // A: m-row / B: n-col
    const int quad = lane >> 4;

    const int bid = blockIdx.x;
    const int g   = bid & 3;            // row-group
    const int cw  = bid >> 2;           // 0..31
    const int r0  = g * 16;
    const int j0  = cw * 16;
    unsigned int* ctrg = ctr + g * 16;  // 64B spacing

    unsigned short* hex0 = hex;
    unsigned short* hex1 = hex + 64 * H_;

    // ---- one-time: weights + bias into LDS ----
    for (int q = tid; q < 48 * 96; q += NTHR) {               // uint4 = 8 bf16
        const int cl = q / 96, c16 = q % 96;
        const int cg = (cl >> 4) * H_ + j0 + (cl & 15);
        *(uint4*)(Wlds + cl * AST + c16 * 8) = *(const uint4*)(Wb + (size_t)cg * K_ + c16 * 8);
    }
    if (tid < 48) bl[tid] = bias[(tid >> 4) * H_ + j0 + (tid & 15)];

    // ---- stage x(0) into A[.,0..255] ----
    for (int q = tid; q < 1024; q += NTHR) {
        const int row = q >> 6, k4 = (q & 63) * 4;
        const float4 v = *(const float4*)(x + ((size_t)(r0 + row) * S_ + 0) * I_ + k4);
        unsigned long long pk = (unsigned long long)f2bf(v.x)
                              | ((unsigned long long)f2bf(v.y) << 16)
                              | ((unsigned long long)f2bf(v.z) << 32)
                              | ((unsigned long long)f2bf(v.w) << 48);
        *(unsigned long long*)(Alds + row * AST + k4) = pk;
    }
    __syncthreads();

    f4v accX = {0.f, 0.f, 0.f, 0.f};
    for (int kt = kp; kt < 8; kt += 2) {                      // x-part: k-tiles 0..7
        s8v a = *(const s8v*)(Alds + mrow * AST + kt * 32 + quad * 8);
        s8v b = *(const s8v*)(Wlds + (nt * 16 + mrow) * AST + kt * 32 + quad * 8);
        accX = __builtin_amdgcn_mfma_f32_16x16x32_bf16(a, b, accX, 0, 0, 0);
    }

    for (int t = 0; t < S_; ++t) {
        // ---- wait for h_{t-1} from the whole row-group ----
        if (tid == 0) {
            while (__hip_atomic_load(ctrg, __ATOMIC_ACQUIRE, __HIP_MEMORY_SCOPE_AGENT)
                   < 32u * (unsigned)t)
                __builtin_amdgcn_s_sleep(2);
        }
        __syncthreads();

        // ---- stage h_{t-1} (bf16) into A[.,256..767] ----
        const unsigned short* hsrc = (t & 1) ? hex1 : hex0;
        for (int q = tid; q < 1024; q += NTHR) {
            const int row = q >> 6, k8 = (q & 63) * 8;
            *(uint4*)(Alds + row * AST + I_ + k8) =
                *(const uint4*)(hsrc + (size_t)(r0 + row) * H_ + k8);
        }
        __syncthreads();

        // ---- recurrent MFMAs: k-tiles 8..23 ----
        f4v accH = {0.f, 0.f, 0.f, 0.f};
        for (int kt = 8 + kp; kt < 24; kt += 2) {
            s8v a = *(const s8v*)(Alds + mrow * AST + kt * 32 + quad * 8);
            s8v b = *(const s8v*)(Wlds + (nt * 16 + mrow) * AST + kt * 32 + quad * 8);
            accH = __builtin_amdgcn_mfma_f32_16x16x32_bf16(a, b, accH, 0, 0, 0);
        }

        // ---- combine partial C-frags in LDS (C/D: col=lane&15, row=quad*4+reg) ----
        if (kp == 0) {
            #pragma unroll
            for (int r = 0; r < 4; ++r)
                Glds[nt][quad * 4 + r][mrow] = accX[r] + accH[r];
        }
        __syncthreads();
        if (kp == 1) {
            #pragma unroll
            for (int r = 0; r < 4; ++r)
                Glds[nt][quad * 4 + r][mrow] += accX[r] + accH[r];
        }
        __syncthreads();

        // ---- epilogue: activations + writes ----
        unsigned short* hdst = (t & 1) ? hex0 : hex1;
        if (tid < 256) {
            const int m = tid >> 4, j = tid & 15;
            const float gi = Glds[0][m][j] + bl[j];
            const float gg = Glds[1][m][j] + bl[16 + j];
            const float go = Glds[2][m][j] + bl[32 + j];
            const float it = sigm(gi);
            const float gt = tanh_(gg);
            const float ot = sigm(go);
            const float ct = it * gt;
            const float ht = ot * tanh_(ct);
            hidden[((size_t)(r0 + m) * S_ + t) * H_ + j0 + j] = ht;
            hdst[(size_t)(r0 + m) * H_ + j0 + j] = f2bf(ht);
            if (t == S_ - 1) {
                hf[(size_t)(r0 + m) * H_ + j0 + j] = ht;
                cf[(size_t)(r0 + m) * H_ + j0 + j] = ct;
            }
        }
        __threadfence();
        __syncthreads();

        // ---- arrive: h_t visible ----
        if (tid == 0)
            __hip_atomic_fetch_add(ctrg, 1u, __ATOMIC_RELEASE, __HIP_MEMORY_SCOPE_AGENT);

        // ---- overlap: stage + compute x-part for t+1 while others arrive ----
        if (t + 1 < S_) {
            for (int q = tid; q < 1024; q += NTHR) {
                const int row = q >> 6, k4 = (q & 63) * 4;
                const float4 v = *(const float4*)(x + ((size_t)(r0 + row) * S_ + (t + 1)) * I_ + k4);
                unsigned long long pk = (unsigned long long)f2bf(v.x)
                                      | ((unsigned long long)f2bf(v.y) << 16)
                                      | ((unsigned long long)f2bf(v.z) << 32)
                                      | ((unsigned long long)f2bf(v.w) << 48);
                *(unsigned long long*)(Alds + row * AST + k4) = pk;
            }
            __syncthreads();
            f4v ax = {0.f, 0.f, 0.f, 0.f};
            for (int kt = kp; kt < 8; kt += 2) {
                s8v a = *(const s8v*)(Alds + mrow * AST + kt * 32 + quad * 8);
                s8v b = *(const s8v*)(Wlds + (nt * 16 + mrow) * AST + kt * 32 + quad * 8);
                ax = __builtin_amdgcn_mfma_f32_16x16x32_bf16(a, b, ax, 0, 0, 0);
            }
            accX = ax;
        }
    }
}

extern "C" void kernel_launch(void* const* d_in, const int* in_sizes, int n_in,
                              void* d_out, int out_size, void* d_ws, size_t ws_size,
                              hipStream_t stream) {
    const float* x    = (const float*)d_in[0];
    const float* W    = (const float*)d_in[1];
    const float* U    = (const float*)d_in[2];
    const float* bias = (const float*)d_in[3];

    float* out    = (float*)d_out;
    float* hidden = out;
    float* hf     = out + (size_t)B_ * S_ * H_;
    float* cf     = hf + (size_t)B_ * H_;

    // ws layout: Wb bf16 (1536x768) | hex 2x(64x512) bf16 | ctr (4 x 64B)
    unsigned short* Wb  = (unsigned short*)d_ws;
    unsigned short* hex = Wb + (size_t)G3 * K_;
    unsigned int*   ctr = (unsigned int*)(hex + 2 * 64 * H_);

    // zero hex (t=0 reads buffer 0) + counters
    hipMemsetAsync(hex, 0, 2 * 64 * H_ * sizeof(unsigned short) + 256, stream);
    hipLaunchKernelGGL(prep_w, dim3(12, 24), dim3(256), 0, stream, W, U, Wb);
    hipLaunchKernelGGL(lstm_persist, dim3(NWG), dim3(NTHR), 0, stream,
                       x, bias, Wb, hex, ctr, hidden, hf, cf);
}